// Round 8
// baseline (302.756 us; speedup 1.0000x reference)
//
#include <hip/hip_runtime.h>
#include <hip/hip_bf16.h>

typedef __hip_bfloat16 bf16;
typedef __attribute__((ext_vector_type(8))) short bf16x8;
typedef __attribute__((ext_vector_type(8))) unsigned short u16x8;
typedef __attribute__((ext_vector_type(4))) float f32x4;
typedef __attribute__((ext_vector_type(4))) int i32x4;
typedef __attribute__((ext_vector_type(4))) short s16x4;

__device__ __forceinline__ float b2f(unsigned short u) {
  return __uint_as_float(((unsigned)u) << 16);
}
__device__ __forceinline__ unsigned short f2b(float x) {
  bf16 h = __float2bfloat16(x);
  return *reinterpret_cast<unsigned short*>(&h);
}

// ============== passA: coarse hist of dst AND src + dtype probe ==============
__global__ void k_passA(const int* __restrict__ src, const int* __restrict__ dst, int E,
                        int nbuck, int M, int* __restrict__ counts,
                        const unsigned short* __restrict__ raw, int* __restrict__ flag) {
  if (blockIdx.x == 256) {
    __shared__ int sbad, snz;
    const int t = threadIdx.x;
    if (t == 0) { sbad = 0; snz = 0; }
    __syncthreads();
    const unsigned short u = raw[t];
    const float a = fabsf(b2f(u));
    if (!(a < 100.f)) atomicAdd(&sbad, 1);
    if (((t & 1) == 0) && u != 0) atomicAdd(&snz, 1);
    __syncthreads();
    if (t == 0) flag[0] = (sbad == 0 && snz > 0) ? 1 : 0;
    return;
  }
  extern __shared__ int lh[];  // lh1[nbuck] then lh2[nbuck]
  int* lh1 = lh;
  int* lh2 = lh + nbuck;
  const int t = threadIdx.x;
  for (int k = t; k < 2 * nbuck; k += 256) lh[k] = 0;
  __syncthreads();
  const int chunk = (E + 255) / 256;
  const int s = blockIdx.x * chunk;
  const int e = min(E, s + chunk);
  for (int i = s + t; i < e; i += 256) {
    atomicAdd(&lh1[dst[i] >> 8], 1);
    atomicAdd(&lh2[src[i] >> 8], 1);
  }
  __syncthreads();
  for (int k = t; k < nbuck; k += 256) {
    counts[k * 256 + blockIdx.x] = lh1[k];
    counts[M + k * 256 + blockIdx.x] = lh2[k];
  }
}

// prepW: one-time W1/W2 -> bf16 W^T [n][k] tables (8KB each, L2-hot for fused gemm)
__global__ void k_prepW(const void* __restrict__ W1, const void* __restrict__ W2,
                        const int* __restrict__ flag,
                        unsigned short* __restrict__ WT1, unsigned short* __restrict__ WT2) {
  const bool isb = (*flag != 0);
  const int i = blockIdx.x * 256 + threadIdx.x;  // 0..8191
  const int j = i & 4095;
  const int n = j >> 6, k = j & 63;
  const void* W = (i < 4096) ? W1 : W2;
  unsigned short* WT = (i < 4096) ? WT1 : WT2;
  const float v = isb ? b2f(((const unsigned short*)W)[k * 64 + n])
                      : ((const float*)W)[k * 64 + n];
  WT[j] = f2b(v);
}

// exclusive scan over 2M ints
__global__ void k_scan1(const int* __restrict__ a, int M2, int* __restrict__ bsums) {
  __shared__ int sdata[256];
  int i = blockIdx.x * 256 + threadIdx.x;
  int v = (i < M2) ? a[i] : 0;
  sdata[threadIdx.x] = v;
  __syncthreads();
  for (int s = 128; s > 0; s >>= 1) {
    if (threadIdx.x < s) sdata[threadIdx.x] += sdata[threadIdx.x + s];
    __syncthreads();
  }
  if (threadIdx.x == 0) bsums[blockIdx.x] = sdata[0];
}

__global__ void k_scan2(int* __restrict__ bsums, int nb, int* __restrict__ rowStart,
                        int N, int E) {
  __shared__ int s[1024];
  const int t = threadIdx.x;
  const int v = (t < nb) ? bsums[t] : 0;
  s[t] = v;
  __syncthreads();
  for (int off = 1; off < 1024; off <<= 1) {
    int u = (t >= off) ? s[t - off] : 0;
    __syncthreads();
    s[t] += u;
    __syncthreads();
  }
  if (t < nb) bsums[t] = s[t] - v;  // exclusive
  if (t == 0) rowStart[N] = E;
}

__global__ void k_scan3(int* __restrict__ a, int M2, const int* __restrict__ bsums) {
  __shared__ int sdata[256];
  int i = blockIdx.x * 256 + threadIdx.x;
  int v = (i < M2) ? a[i] : 0;
  sdata[threadIdx.x] = v;
  __syncthreads();
  for (int off = 1; off < 256; off <<= 1) {
    int t = (threadIdx.x >= off) ? sdata[threadIdx.x - off] : 0;
    __syncthreads();
    sdata[threadIdx.x] += t;
    __syncthreads();
  }
  if (i < M2) a[i] = bsums[blockIdx.x] + sdata[threadIdx.x] - v;  // exclusive
}

// passC: dual scatter via LDS cursors — ZERO global atomics.
__global__ void k_passC(const int* __restrict__ src, const int* __restrict__ dst, int E,
                        int nbuck, int M, const int* __restrict__ S,
                        int* __restrict__ tmp, unsigned char* __restrict__ tmp2) {
  extern __shared__ int cur[];  // cur1[nbuck], cur2[nbuck]
  int* cur1 = cur;
  int* cur2 = cur + nbuck;
  const int t = threadIdx.x;
  for (int k = t; k < nbuck; k += 256) {
    cur1[k] = S[k * 256 + blockIdx.x];
    cur2[k] = S[M + k * 256 + blockIdx.x];
  }
  __syncthreads();
  const int chunk = (E + 255) / 256;
  const int s = blockIdx.x * chunk;
  const int e = min(E, s + chunk);
  for (int i = s + t; i < e; i += 256) {
    const int sv = src[i];
    const int d = dst[i];
    const int pos1 = atomicAdd(&cur1[d >> 8], 1);
    tmp[pos1] = sv | ((d & 255) << 20);
    const int pos2 = atomicAdd(&cur2[sv >> 8], 1);
    tmp2[pos2 - E] = (unsigned char)(sv & 255);
  }
}

// passD: per bucket k: (1) src-side byte hist -> deg_out -> ns;
//        (2) dst-side hist + scan -> rowStart, nd, edgeSrc scatter.
__global__ void k_passD(const int* __restrict__ tmp, const unsigned char* __restrict__ tmp2,
                        const int* __restrict__ S, int nbuck, int M, int N, int E,
                        int* __restrict__ rowStart, int* __restrict__ edgeSrc,
                        float* __restrict__ ns, float* __restrict__ nd) {
  __shared__ int h[256];
  __shared__ int ex[256];
  __shared__ int c[256];
  const int t = threadIdx.x;
  const int k = blockIdx.x;
  const int node = k * 256 + t;
  const int bs2 = S[M + k * 256] - E;
  const int be2 = (k + 1 < nbuck) ? (S[M + (k + 1) * 256] - E) : E;
  h[t] = 0;
  __syncthreads();
  for (int i = bs2 + t; i < be2; i += 256) atomicAdd(&h[tmp2[i]], 1);
  __syncthreads();
  if (node < N) {
    int dov = h[t];
    if (dov <= 0) dov = 1;
    ns[node] = rsqrtf((float)dov);
  }
  __syncthreads();
  const int bs = S[k * 256];
  const int be = (k + 1 < nbuck) ? S[(k + 1) * 256] : E;
  h[t] = 0;
  __syncthreads();
  for (int i = bs + t; i < be; i += 256) atomicAdd(&h[tmp[i] >> 20], 1);
  __syncthreads();
  const int cnt = h[t];
  ex[t] = cnt;
  __syncthreads();
  for (int off = 1; off < 256; off <<= 1) {
    int u = (t >= off) ? ex[t - off] : 0;
    __syncthreads();
    ex[t] += u;
    __syncthreads();
  }
  const int excl = ex[t] - cnt;
  if (node < N) {
    rowStart[node] = bs + excl;
    nd[node] = rsqrtf((float)(cnt > 0 ? cnt : 1));
  }
  c[t] = bs + excl;
  __syncthreads();
  for (int i = bs + t; i < be; i += 256) {
    const int v = tmp[i];
    const int pos = atomicAdd(&c[v >> 20], 1);
    edgeSrc[pos] = v & 0xFFFFF;
  }
}

// ---------------- MFMA GEMM layer-0: 2 groups/wave, A issued up-front ----------------
template <int K, bool FIRST, bool SCALE>
__device__ __forceinline__ void gemm_loadA(const void* hin, bool isb, int rowA,
                                           int quad, bf16x8* A) {
  constexpr int KT = K / 32;
  if (FIRST && !isb) {
    const float* hp = (const float*)hin + (size_t)rowA * K;
#pragma unroll
    for (int kt = 0; kt < KT; ++kt) {
      const float4 u0 = *(const float4*)(hp + kt * 32 + quad * 8);
      const float4 u1 = *(const float4*)(hp + kt * 32 + quad * 8 + 4);
      A[kt][0] = (short)f2b(u0.x); A[kt][1] = (short)f2b(u0.y);
      A[kt][2] = (short)f2b(u0.z); A[kt][3] = (short)f2b(u0.w);
      A[kt][4] = (short)f2b(u1.x); A[kt][5] = (short)f2b(u1.y);
      A[kt][6] = (short)f2b(u1.z); A[kt][7] = (short)f2b(u1.w);
    }
  } else {
    const unsigned short* hp = (const unsigned short*)hin + (size_t)rowA * K;
#pragma unroll
    for (int kt = 0; kt < KT; ++kt)
      A[kt] = *(const bf16x8*)(hp + kt * 32 + quad * 8);
  }
}

template <int K, bool FIRST, bool SCALE>
__global__ void __launch_bounds__(256) k_gemm(
    const void* __restrict__ hin, const void* __restrict__ Wv,
    const int* __restrict__ flag, const float* __restrict__ norm_src,
    int N, unsigned short* __restrict__ out) {
  constexpr int KT = K / 32;
  constexpr int ST = K + 8;     // W-tile row stride (shorts)
  constexpr int CST = 72;       // C-tile row stride (shorts)
  __shared__ unsigned short Wl[64 * ST];
  __shared__ unsigned short Cl[4][16 * CST];
  const bool isb = (*flag != 0);
  const int tid = threadIdx.x;
  const int lane = tid & 63;
  const int quad = lane >> 4;
  const int l16 = lane & 15;
  const int w = tid >> 6;

  const int wid = blockIdx.x * 4 + w;
  const int nw = gridDim.x * 4;
  const int G = (N + 15) >> 4;
  const int g1 = wid + nw;

  // issue BOTH A-group loads first: 256B/lane outstanding under W staging
  bf16x8 A[2][KT];
  {
    const int r0 = min((wid << 4) + l16, N - 1);
    const int r1 = min((g1 << 4) + l16, N - 1);
    gemm_loadA<K, FIRST, SCALE>(hin, isb, r0, quad, A[0]);
    gemm_loadA<K, FIRST, SCALE>(hin, isb, r1, quad, A[1]);
  }

  // ---- stage W once per block: W[k][n] -> Wl[n][k] (bf16) ----
  {
    const unsigned short* Wus = (const unsigned short*)Wv;
    const float* Wf = (const float*)Wv;
    for (int i0 = tid * 8; i0 < K * 64; i0 += 2048) {
      const int k = i0 >> 6;
      const int n0 = i0 & 63;
      unsigned short v[8];
      if (isb) {
        const u16x8 u = *(const u16x8*)(Wus + i0);
#pragma unroll
        for (int j = 0; j < 8; ++j) v[j] = u[j];
      } else {
        const float4 f0 = *(const float4*)(Wf + i0);
        const float4 f1 = *(const float4*)(Wf + i0 + 4);
        v[0] = f2b(f0.x); v[1] = f2b(f0.y); v[2] = f2b(f0.z); v[3] = f2b(f0.w);
        v[4] = f2b(f1.x); v[5] = f2b(f1.y); v[6] = f2b(f1.z); v[7] = f2b(f1.w);
      }
#pragma unroll
      for (int j = 0; j < 8; ++j) Wl[(n0 + j) * ST + k] = v[j];
    }
  }
  __syncthreads();

  unsigned short* myC = &Cl[w][0];
#pragma unroll
  for (int gi = 0; gi < 2; ++gi) {
    const int g = (gi == 0) ? wid : g1;
    f32x4 acc[4] = {{0.f, 0.f, 0.f, 0.f}, {0.f, 0.f, 0.f, 0.f},
                    {0.f, 0.f, 0.f, 0.f}, {0.f, 0.f, 0.f, 0.f}};
#pragma unroll
    for (int kt = 0; kt < KT; ++kt) {
      const int koff = kt * 32 + quad * 8;
#pragma unroll
      for (int nt = 0; nt < 4; ++nt) {
        const bf16x8 Bf = *(const bf16x8*)&Wl[(nt * 16 + l16) * ST + koff];
        acc[nt] = __builtin_amdgcn_mfma_f32_16x16x32_bf16(A[gi][kt], Bf, acc[nt], 0, 0, 0);
      }
    }
    const int rowD = quad * 4;
#pragma unroll
    for (int r = 0; r < 4; ++r) {
      const int nodeW = min((g << 4) + rowD + r, N - 1);
      const float f = SCALE ? norm_src[nodeW] : 1.0f;
#pragma unroll
      for (int nt = 0; nt < 4; ++nt)
        myC[(rowD + r) * CST + nt * 16 + l16] = f2b(SCALE ? acc[nt][r] * f : acc[nt][r]);
    }
    __builtin_amdgcn_sched_barrier(0);
    const int row2 = lane >> 2;
    const int c0 = (lane & 3) * 16;
    const int node = (g << 4) + row2;
    if (node < N) {
      const u16x8 v0 = *(const u16x8*)&myC[row2 * CST + c0];
      const u16x8 v1 = *(const u16x8*)&myC[row2 * CST + c0 + 8];
      *(u16x8*)(out + (size_t)node * 64 + c0) = v0;
      *(u16x8*)(out + (size_t)node * 64 + c0 + 8) = v1;
    }
  }
}

// ---------------- MFMA aggregation (SpMM, segment-indicator A) + fused next-gemm -----
__device__ __forceinline__ void agg_chunk_compute(unsigned trbase, int cb32, int lo,
                                                  unsigned span, int quad, f32x4* acc) {
  const int posbase = cb32 + (quad << 2);
  const unsigned u0 = (unsigned)(posbase - lo);
  bf16x8 Af;
#pragma unroll
  for (int j = 0; j < 8; ++j) {
    const unsigned off = (j < 4) ? (unsigned)j : (unsigned)(12 + j);
    Af[j] = ((u0 + off) < span) ? (short)0x3F80 : (short)0;
  }
  s16x4 t0[4], t1[4];
#pragma unroll
  for (int nt = 0; nt < 4; ++nt) {
    const unsigned a = trbase + (unsigned)(nt * 1024);
    asm volatile("ds_read_b64_tr_b16 %0, %1" : "=v"(t0[nt]) : "v"(a) : "memory");
    asm volatile("ds_read_b64_tr_b16 %0, %1 offset:512" : "=v"(t1[nt]) : "v"(a) : "memory");
  }
  asm volatile("s_waitcnt lgkmcnt(0)" ::: "memory");
  __builtin_amdgcn_sched_barrier(0);
#pragma unroll
  for (int nt = 0; nt < 4; ++nt) {
    bf16x8 Bf;
    Bf[0] = t0[nt][0]; Bf[1] = t0[nt][1]; Bf[2] = t0[nt][2]; Bf[3] = t0[nt][3];
    Bf[4] = t1[nt][0]; Bf[5] = t1[nt][1]; Bf[6] = t1[nt][2]; Bf[7] = t1[nt][3];
    acc[nt] = __builtin_amdgcn_mfma_f32_16x16x32_bf16(Af, Bf, acc[nt], 0, 0, 0);
  }
}

// FUSE: epilogue computes h=relu(agg*nd+b)*ns into hT (ALIASED onto the gather LDS),
// B-fragments come straight from the pre-transposed bf16 WT table (L2-hot global).
// LDS stays 16KB -> ~2x resident blocks vs round-7's 30KB.
template <bool LAST, bool FUSE>
__global__ void __launch_bounds__(256) k_aggregate(
    const unsigned short* __restrict__ proj,
    const int* __restrict__ edgeSrc, const int* __restrict__ rowStart,
    const float* __restrict__ norm_dst, const float* __restrict__ norm_src,
    const void* __restrict__ bias, const int* __restrict__ flag,
    const unsigned short* __restrict__ WT, int N, int E, void* __restrict__ outp) {
  __shared__ unsigned short lds[4][2048];  // 4 KB per wave: [32 edges][64 cols]
  const bool isb = (*flag != 0);
  const int tid = threadIdx.x;
  const int w = tid >> 6;
  const int lane = tid & 63;
  const int l16 = lane & 15;
  const int quad = lane >> 4;
  const int e32 = lane & 31;
  const int p = lane >> 5;

  const int wid = blockIdx.x * 4 + w;
  const int g0 = wid * 8;

  float bcol[4];
#pragma unroll
  for (int nt = 0; nt < 4; ++nt) {
    const int col = nt * 16 + l16;
    bcol[nt] = isb ? b2f(((const unsigned short*)bias)[col]) : ((const float*)bias)[col];
  }

  const int cb = rowStart[min(g0, N)];
  const int ce = rowStart[min(g0 + 8, N)];
  const int L = ce - cb;
  const int nch = (L + 31) >> 5;

  const int rsi = min(g0 + min(l16, 8), N);
  const int rsj = min(g0 + min(l16 + 1, 8), N);
  const int lo = rowStart[rsi];
  const unsigned span = (unsigned)(rowStart[rsj] - lo);

  int idxc[6];
#pragma unroll
  for (int t = 0; t < 6; ++t) {
    const int pos = min(cb + t * 32 + e32, E - 1);
    idxc[t] = edgeSrc[pos];
  }

  unsigned short* myl = &lds[w][0];
  unsigned wofs[4];
#pragma unroll
  for (int q = 0; q < 4; ++q) {
    const int n0 = p * 32 + q * 8;
    wofs[q] = (unsigned)((n0 >> 4) * 512 + e32 * 16 + (n0 & 15));
  }
  const unsigned trbase = (unsigned)(uintptr_t)myl + (unsigned)lane * 8u;

  f32x4 acc[4] = {{0.f, 0.f, 0.f, 0.f}, {0.f, 0.f, 0.f, 0.f},
                  {0.f, 0.f, 0.f, 0.f}, {0.f, 0.f, 0.f, 0.f}};

  i32x4 gb[2][4];
#define AGG_ISSUE(t, b)                                                         \
  {                                                                             \
    const unsigned short* rp = proj + (size_t)idxc[t] * 64 + p * 32;            \
    gb[b][0] = *(const i32x4*)(rp);                                             \
    gb[b][1] = *(const i32x4*)(rp + 8);                                         \
    gb[b][2] = *(const i32x4*)(rp + 16);                                        \
    gb[b][3] = *(const i32x4*)(rp + 24);                                        \
  }
  if (0 < nch) AGG_ISSUE(0, 0);
  if (1 < nch) AGG_ISSUE(1, 1);

#pragma unroll
  for (int tt = 0; tt < 6; ++tt) {
    if (tt < nch) {
#pragma unroll
      for (int q = 0; q < 4; ++q) *(i32x4*)(myl + wofs[q]) = gb[tt & 1][q];
      if (tt + 2 < 6 && tt + 2 < nch) AGG_ISSUE(tt + 2, tt & 1);
      asm volatile("s_waitcnt lgkmcnt(0)" ::: "memory");
      agg_chunk_compute(trbase, cb + tt * 32, lo, span, quad, acc);
    }
  }
  for (int t = 6; t < nch; ++t) {
    const int pos = min(cb + t * 32 + e32, E - 1);
    const int idx = edgeSrc[pos];
    const unsigned short* rp = proj + (size_t)idx * 64 + p * 32;
    i32x4 g4[4];
    g4[0] = *(const i32x4*)(rp);
    g4[1] = *(const i32x4*)(rp + 8);
    g4[2] = *(const i32x4*)(rp + 16);
    g4[3] = *(const i32x4*)(rp + 24);
#pragma unroll
    for (int q = 0; q < 4; ++q) *(i32x4*)(myl + wofs[q]) = g4[q];
    asm volatile("s_waitcnt lgkmcnt(0)" ::: "memory");
    agg_chunk_compute(trbase, cb + t * 32, lo, span, quad, acc);
  }
#undef AGG_ISSUE

  if constexpr (FUSE) {
    // ---- fused epilogue: h -> hT (aliased) -> h @ WT -> proj stores ----
    __syncthreads();  // all waves done with their gather tiles before aliasing
    unsigned short* hT = &lds[0][0];  // 32 x 72 (144B row stride, 16B-aligned)
    const int r0 = (w & 1) * 16;
    const int cb2 = (w >> 1) * 32;
    // B-fragments from the 8KB pre-transposed WT table (L2-hot, 4x16B/lane)
    bf16x8 Bfr[2][2];
#pragma unroll
    for (int kt = 0; kt < 2; ++kt) {
      const int koff = kt * 32 + quad * 8;
#pragma unroll
      for (int nt = 0; nt < 2; ++nt)
        Bfr[kt][nt] = *(const bf16x8*)(WT + (size_t)(cb2 + nt * 16 + l16) * 64 + koff);
    }
#pragma unroll
    for (int reg = 0; reg < 4; ++reg) {
      const int row = quad * 4 + reg;
      if (row < 8) {
        const int node = min(g0 + row, N - 1);
        const float nd = norm_dst[node];
        const float esc = norm_src[node];
#pragma unroll
        for (int nt = 0; nt < 4; ++nt) {
          const float x = fmaxf(fmaf(acc[nt][reg], nd, bcol[nt]), 0.f) * esc;
          hT[(w * 8 + row) * 72 + nt * 16 + l16] = f2b(x);
        }
      }
    }
    __syncthreads();
    // each wave: 16 rows x 32 cols of proj = h @ W
    bf16x8 Afr[2];
#pragma unroll
    for (int kt = 0; kt < 2; ++kt)
      Afr[kt] = *(const bf16x8*)&hT[(r0 + l16) * 72 + kt * 32 + quad * 8];
    f32x4 acc2[2] = {{0.f, 0.f, 0.f, 0.f}, {0.f, 0.f, 0.f, 0.f}};
#pragma unroll
    for (int kt = 0; kt < 2; ++kt)
#pragma unroll
      for (int nt = 0; nt < 2; ++nt)
        acc2[nt] = __builtin_amdgcn_mfma_f32_16x16x32_bf16(Afr[kt], Bfr[kt][nt], acc2[nt], 0, 0, 0);
    __syncthreads();  // all A LDS reads complete before hT is overwritten
#pragma unroll
    for (int nt = 0; nt < 2; ++nt)
#pragma unroll
      for (int reg = 0; reg < 4; ++reg) {
        const int row = r0 + quad * 4 + reg;
        hT[row * 72 + cb2 + nt * 16 + l16] = f2b(acc2[nt][reg]);
      }
    __syncthreads();
    const int row = tid >> 3;
    const int c0 = (tid & 7) * 8;
    const int node = blockIdx.x * 32 + row;
    if (node < N) {
      *(u16x8*)((unsigned short*)outp + (size_t)node * 64 + c0) =
          *(const u16x8*)&hT[row * 72 + c0];
    }
  } else {
    // ---- LAST epilogue: finalize -> stage[w] -> coalesced stores ----
    if (!isb) {
      float* fs = (float*)myl;
#pragma unroll
      for (int reg = 0; reg < 4; ++reg) {
        const int row = quad * 4 + reg;
        if (row < 8) {
          const int node = min(g0 + row, N - 1);
          const float nd = norm_dst[node];
#pragma unroll
          for (int nt = 0; nt < 4; ++nt)
            fs[row * 64 + nt * 16 + l16] = fmaxf(fmaf(acc[nt][reg], nd, bcol[nt]), 0.f);
        }
      }
      asm volatile("s_waitcnt lgkmcnt(0)" ::: "memory");
      __builtin_amdgcn_sched_barrier(0);
      const int r = lane >> 3;
      const int c0 = (lane & 7) * 8;
      const int node = g0 + r;
      if (node < N) {
        const float4 v0 = *(const float4*)&fs[r * 64 + c0];
        const float4 v1 = *(const float4*)&fs[r * 64 + c0 + 4];
        float* of = (float*)outp + (size_t)node * 64 + c0;
        *(float4*)of = v0;
        *(float4*)(of + 4) = v1;
      }
    } else {
#pragma unroll
      for (int reg = 0; reg < 4; ++reg) {
        const int row = quad * 4 + reg;
        if (row < 8) {
          const int node = min(g0 + row, N - 1);
          const float nd = norm_dst[node];
#pragma unroll
          for (int nt = 0; nt < 4; ++nt) {
            const float x = fmaxf(fmaf(acc[nt][reg], nd, bcol[nt]), 0.f);
            myl[row * 64 + nt * 16 + l16] = f2b(x);
          }
        }
      }
      asm volatile("s_waitcnt lgkmcnt(0)" ::: "memory");
      __builtin_amdgcn_sched_barrier(0);
      if (lane < 32) {
        const int r = lane >> 2;
        const int c0 = (lane & 3) * 16;
        const int node = g0 + r;
        if (node < N) {
          const u16x8 v0 = *(const u16x8*)&myl[r * 64 + c0];
          const u16x8 v1 = *(const u16x8*)&myl[r * 64 + c0 + 8];
          *(u16x8*)((unsigned short*)outp + (size_t)node * 64 + c0) = v0;
          *(u16x8*)((unsigned short*)outp + (size_t)node * 64 + c0 + 8) = v1;
        }
      }
    }
  }
}

extern "C" void kernel_launch(void* const* d_in, const int* in_sizes, int n_in,
                              void* d_out, int out_size, void* d_ws, size_t ws_size,
                              hipStream_t stream) {
  const void* features = d_in[0];
  const void* W0 = d_in[1];
  const void* b0 = d_in[2];
  const void* W1 = d_in[3];
  const void* b1 = d_in[4];
  const void* W2 = d_in[5];
  const void* b2 = d_in[6];
  const int* src = (const int*)d_in[7];
  const int* dst = (const int*)d_in[8];
  const int N = in_sizes[0] / 128;
  const int E = in_sizes[7];
  const int NBUCK = (N + 255) >> 8;
  const int M = NBUCK * 256;
  const int M2 = 2 * M;

  char* w = (char*)d_ws;
  size_t off = 0;
  auto alloc = [&](size_t bytes) {
    void* p = w + off;
    off = (off + bytes + 255) & ~(size_t)255;
    return p;
  };
  int* flag = (int*)alloc(4);
  int* rowStart = (int*)alloc((size_t)(N + 1) * 4);
  int* counts = (int*)alloc((size_t)M2 * 4);
  int* bsums = (int*)alloc(1024 * 4);
  float* norm_src = (float*)alloc((size_t)N * 4);
  float* norm_dst = (float*)alloc((size_t)N * 4);
  int* tmp = (int*)alloc((size_t)E * 4);
  unsigned char* tmp2 = (unsigned char*)alloc((size_t)E);
  int* edgeSrc = (int*)alloc((size_t)E * 4);
  unsigned short* projA = (unsigned short*)alloc((size_t)N * 64 * 2);  // bf16
  unsigned short* projB = (unsigned short*)alloc((size_t)N * 64 * 2);  // bf16
  unsigned short* WT1 = (unsigned short*)alloc(64 * 64 * 2);
  unsigned short* WT2 = (unsigned short*)alloc(64 * 64 * 2);

  const size_t lds_nb = (size_t)NBUCK * 2 * 4;  // dual hist/cursors
  const int G16 = (N + 15) / 16;                // 16-row groups
  const int GB = (G16 + 7) / 8;                 // exactly 2 groups per wave

  // CSR build — zero global atomics end-to-end, no memset needed.
  k_passA<<<257, 256, lds_nb, stream>>>(src, dst, E, NBUCK, M, counts,
                                        (const unsigned short*)features, flag);
  k_prepW<<<32, 256, 0, stream>>>(W1, W2, flag, WT1, WT2);
  const int NB2 = (M2 + 255) / 256;  // == 2*NBUCK
  k_scan1<<<NB2, 256, 0, stream>>>(counts, M2, bsums);
  k_scan2<<<1, 1024, 0, stream>>>(bsums, NB2, rowStart, N, E);
  k_scan3<<<NB2, 256, 0, stream>>>(counts, M2, bsums);
  k_passC<<<256, 256, lds_nb, stream>>>(src, dst, E, NBUCK, M, counts, tmp, tmp2);
  k_passD<<<NBUCK, 256, 0, stream>>>(tmp, tmp2, counts, NBUCK, M, N, E,
                                     rowStart, edgeSrc, norm_src, norm_dst);

  const int AB = (((N + 7) / 8) + 3) / 4;  // 8 nodes/wave, 4 waves/block (32/block)
  // layer 0 gemm (ns folded into epilogue)
  k_gemm<128, true, true><<<GB, 256, 0, stream>>>(features, W0, flag, norm_src, N, projA);
  // agg0 + fused gemm1 -> projB
  k_aggregate<false, true><<<AB, 256, 0, stream>>>(projA, edgeSrc, rowStart, norm_dst,
                                                   norm_src, b0, flag, WT1, N, E, projB);
  // agg1 + fused gemm2 -> projA
  k_aggregate<false, true><<<AB, 256, 0, stream>>>(projB, edgeSrc, rowStart, norm_dst,
                                                   norm_src, b1, flag, WT2, N, E, projA);
  // agg2 (LAST) -> d_out
  k_aggregate<true, false><<<AB, 256, 0, stream>>>(projA, edgeSrc, rowStart, norm_dst,
                                                   norm_src, b2, flag, nullptr, N, E, d_out);
}

// Round 9
// 289.330 us; speedup vs baseline: 1.0464x; 1.0464x over previous
//
#include <hip/hip_runtime.h>
#include <hip/hip_bf16.h>

typedef __hip_bfloat16 bf16;
typedef __attribute__((ext_vector_type(8))) short bf16x8;
typedef __attribute__((ext_vector_type(8))) unsigned short u16x8;
typedef __attribute__((ext_vector_type(4))) float f32x4;
typedef __attribute__((ext_vector_type(4))) int i32x4;
typedef __attribute__((ext_vector_type(4))) short s16x4;

__device__ __forceinline__ float b2f(unsigned short u) {
  return __uint_as_float(((unsigned)u) << 16);
}
__device__ __forceinline__ unsigned short f2b(float x) {
  bf16 h = __float2bfloat16(x);
  return *reinterpret_cast<unsigned short*>(&h);
}

// ============== passA: coarse hist of dst AND src + dtype probe (1024 thr) ==========
__global__ void __launch_bounds__(1024) k_passA(
    const int* __restrict__ src, const int* __restrict__ dst, int E,
    int nbuck, int M, int* __restrict__ counts,
    const unsigned short* __restrict__ raw, int* __restrict__ flag) {
  const int t = threadIdx.x;
  if (blockIdx.x == 256) {
    __shared__ int sbad, snz;
    if (t == 0) { sbad = 0; snz = 0; }
    __syncthreads();
    if (t < 256) {
      const unsigned short u = raw[t];
      const float a = fabsf(b2f(u));
      if (!(a < 100.f)) atomicAdd(&sbad, 1);
      if (((t & 1) == 0) && u != 0) atomicAdd(&snz, 1);
    }
    __syncthreads();
    if (t == 0) flag[0] = (sbad == 0 && snz > 0) ? 1 : 0;
    return;
  }
  extern __shared__ int lh[];  // lh1[nbuck] then lh2[nbuck]
  int* lh1 = lh;
  int* lh2 = lh + nbuck;
  for (int k = t; k < 2 * nbuck; k += 1024) lh[k] = 0;
  __syncthreads();
  const int chunk = (E + 255) / 256;
  const int s = blockIdx.x * chunk;
  const int e = min(E, s + chunk);
  for (int i = s + t; i < e; i += 1024) {
    atomicAdd(&lh1[dst[i] >> 8], 1);
    atomicAdd(&lh2[src[i] >> 8], 1);
  }
  __syncthreads();
  for (int k = t; k < nbuck; k += 1024) {
    counts[k * 256 + blockIdx.x] = lh1[k];
    counts[M + k * 256 + blockIdx.x] = lh2[k];
  }
}

// exclusive scan over 2M ints
__global__ void k_scan1(const int* __restrict__ a, int M2, int* __restrict__ bsums) {
  __shared__ int sdata[256];
  int i = blockIdx.x * 256 + threadIdx.x;
  int v = (i < M2) ? a[i] : 0;
  sdata[threadIdx.x] = v;
  __syncthreads();
  for (int s = 128; s > 0; s >>= 1) {
    if (threadIdx.x < s) sdata[threadIdx.x] += sdata[threadIdx.x + s];
    __syncthreads();
  }
  if (threadIdx.x == 0) bsums[blockIdx.x] = sdata[0];
}

// block 0: scan over bsums; blocks >=1: prepW (W1/W2 -> bf16 W^T tables)
__global__ void __launch_bounds__(1024) k_scan2(
    int* __restrict__ bsums, int nb, int* __restrict__ rowStart, int N, int E,
    const void* __restrict__ W1, const void* __restrict__ W2,
    const int* __restrict__ flag,
    unsigned short* __restrict__ WT1, unsigned short* __restrict__ WT2) {
  const int t = threadIdx.x;
  if (blockIdx.x > 0) {
    const int i = (blockIdx.x - 1) * 1024 + t;  // 0..8191
    if (i < 8192) {
      const bool isb = (*flag != 0);
      const int j = i & 4095;
      const int n = j >> 6, k = j & 63;
      const void* W = (i < 4096) ? W1 : W2;
      unsigned short* WT = (i < 4096) ? WT1 : WT2;
      const float v = isb ? b2f(((const unsigned short*)W)[k * 64 + n])
                          : ((const float*)W)[k * 64 + n];
      WT[j] = f2b(v);
    }
    return;
  }
  __shared__ int s[1024];
  const int v = (t < nb) ? bsums[t] : 0;
  s[t] = v;
  __syncthreads();
  for (int off = 1; off < 1024; off <<= 1) {
    int u = (t >= off) ? s[t - off] : 0;
    __syncthreads();
    s[t] += u;
    __syncthreads();
  }
  if (t < nb) bsums[t] = s[t] - v;  // exclusive
  if (t == 0) rowStart[N] = E;
}

__global__ void k_scan3(int* __restrict__ a, int M2, const int* __restrict__ bsums) {
  __shared__ int sdata[256];
  int i = blockIdx.x * 256 + threadIdx.x;
  int v = (i < M2) ? a[i] : 0;
  sdata[threadIdx.x] = v;
  __syncthreads();
  for (int off = 1; off < 256; off <<= 1) {
    int t = (threadIdx.x >= off) ? sdata[threadIdx.x - off] : 0;
    __syncthreads();
    sdata[threadIdx.x] += t;
    __syncthreads();
  }
  if (i < M2) a[i] = bsums[blockIdx.x] + sdata[threadIdx.x] - v;  // exclusive
}

// passC: dual scatter via LDS cursors — ZERO global atomics (1024 thr).
__global__ void __launch_bounds__(1024) k_passC(
    const int* __restrict__ src, const int* __restrict__ dst, int E,
    int nbuck, int M, const int* __restrict__ S,
    int* __restrict__ tmp, unsigned char* __restrict__ tmp2) {
  extern __shared__ int cur[];  // cur1[nbuck], cur2[nbuck]
  int* cur1 = cur;
  int* cur2 = cur + nbuck;
  const int t = threadIdx.x;
  for (int k = t; k < nbuck; k += 1024) {
    cur1[k] = S[k * 256 + blockIdx.x];
    cur2[k] = S[M + k * 256 + blockIdx.x];
  }
  __syncthreads();
  const int chunk = (E + 255) / 256;
  const int s = blockIdx.x * chunk;
  const int e = min(E, s + chunk);
  for (int i = s + t; i < e; i += 1024) {
    const int sv = src[i];
    const int d = dst[i];
    const int pos1 = atomicAdd(&cur1[d >> 8], 1);
    tmp[pos1] = sv | ((d & 255) << 20);
    const int pos2 = atomicAdd(&cur2[sv >> 8], 1);
    tmp2[pos2 - E] = (unsigned char)(sv & 255);
  }
}

// passD: per bucket (1024 thr): (1) src byte hist -> ns; (2) dst hist+scan ->
// rowStart, nd, edgeSrc. Streaming loops use all 1024; per-node work gated t<256.
__global__ void __launch_bounds__(1024) k_passD(
    const int* __restrict__ tmp, const unsigned char* __restrict__ tmp2,
    const int* __restrict__ S, int nbuck, int M, int N, int E,
    int* __restrict__ rowStart, int* __restrict__ edgeSrc,
    float* __restrict__ ns, float* __restrict__ nd) {
  __shared__ int h[256];
  __shared__ int ex[256];
  __shared__ int c[256];
  const int t = threadIdx.x;
  const int k = blockIdx.x;
  const int node = k * 256 + t;  // valid for t<256
  // ---- phase 1: src-side (deg_out -> ns) ----
  const int bs2 = S[M + k * 256] - E;
  const int be2 = (k + 1 < nbuck) ? (S[M + (k + 1) * 256] - E) : E;
  if (t < 256) h[t] = 0;
  __syncthreads();
  for (int i = bs2 + t; i < be2; i += 1024) atomicAdd(&h[tmp2[i]], 1);
  __syncthreads();
  if (t < 256 && node < N) {
    int dov = h[t];
    if (dov <= 0) dov = 1;
    ns[node] = rsqrtf((float)dov);
  }
  __syncthreads();
  // ---- phase 2: dst-side (rowStart, nd, edgeSrc) ----
  const int bs = S[k * 256];
  const int be = (k + 1 < nbuck) ? S[(k + 1) * 256] : E;
  if (t < 256) h[t] = 0;
  __syncthreads();
  for (int i = bs + t; i < be; i += 1024) atomicAdd(&h[tmp[i] >> 20], 1);
  __syncthreads();
  int cnt = 0;
  if (t < 256) {
    cnt = h[t];
    ex[t] = cnt;
  }
  __syncthreads();
  for (int off = 1; off < 256; off <<= 1) {
    int u = (t < 256 && t >= off) ? ex[t - off] : 0;
    __syncthreads();
    if (t < 256) ex[t] += u;
    __syncthreads();
  }
  if (t < 256) {
    const int excl = ex[t] - cnt;
    if (node < N) {
      rowStart[node] = bs + excl;
      nd[node] = rsqrtf((float)(cnt > 0 ? cnt : 1));
    }
    c[t] = bs + excl;
  }
  __syncthreads();
  for (int i = bs + t; i < be; i += 1024) {
    const int v = tmp[i];
    const int pos = atomicAdd(&c[v >> 20], 1);
    edgeSrc[pos] = v & 0xFFFFF;
  }
}

// ---------------- MFMA GEMM layer-0: 2 groups/wave, A issued up-front ----------------
template <int K, bool FIRST, bool SCALE>
__device__ __forceinline__ void gemm_loadA(const void* hin, bool isb, int rowA,
                                           int quad, bf16x8* A) {
  constexpr int KT = K / 32;
  if (FIRST && !isb) {
    const float* hp = (const float*)hin + (size_t)rowA * K;
#pragma unroll
    for (int kt = 0; kt < KT; ++kt) {
      const float4 u0 = *(const float4*)(hp + kt * 32 + quad * 8);
      const float4 u1 = *(const float4*)(hp + kt * 32 + quad * 8 + 4);
      A[kt][0] = (short)f2b(u0.x); A[kt][1] = (short)f2b(u0.y);
      A[kt][2] = (short)f2b(u0.z); A[kt][3] = (short)f2b(u0.w);
      A[kt][4] = (short)f2b(u1.x); A[kt][5] = (short)f2b(u1.y);
      A[kt][6] = (short)f2b(u1.z); A[kt][7] = (short)f2b(u1.w);
    }
  } else {
    const unsigned short* hp = (const unsigned short*)hin + (size_t)rowA * K;
#pragma unroll
    for (int kt = 0; kt < KT; ++kt)
      A[kt] = *(const bf16x8*)(hp + kt * 32 + quad * 8);
  }
}

template <int K, bool FIRST, bool SCALE>
__global__ void __launch_bounds__(256) k_gemm(
    const void* __restrict__ hin, const void* __restrict__ Wv,
    const int* __restrict__ flag, const float* __restrict__ norm_src,
    int N, unsigned short* __restrict__ out) {
  constexpr int KT = K / 32;
  constexpr int ST = K + 8;     // W-tile row stride (shorts)
  constexpr int CST = 72;       // C-tile row stride (shorts)
  __shared__ unsigned short Wl[64 * ST];
  __shared__ unsigned short Cl[4][16 * CST];
  const bool isb = (*flag != 0);
  const int tid = threadIdx.x;
  const int lane = tid & 63;
  const int quad = lane >> 4;
  const int l16 = lane & 15;
  const int w = tid >> 6;

  const int wid = blockIdx.x * 4 + w;
  const int nw = gridDim.x * 4;
  const int G = (N + 15) >> 4;
  const int g1 = wid + nw;

  // issue BOTH A-group loads first: 256B/lane outstanding under W staging
  bf16x8 A[2][KT];
  {
    const int r0 = min((wid << 4) + l16, N - 1);
    const int r1 = min((g1 << 4) + l16, N - 1);
    gemm_loadA<K, FIRST, SCALE>(hin, isb, r0, quad, A[0]);
    gemm_loadA<K, FIRST, SCALE>(hin, isb, r1, quad, A[1]);
  }

  // ---- stage W once per block: W[k][n] -> Wl[n][k] (bf16) ----
  {
    const unsigned short* Wus = (const unsigned short*)Wv;
    const float* Wf = (const float*)Wv;
    for (int i0 = tid * 8; i0 < K * 64; i0 += 2048) {
      const int k = i0 >> 6;
      const int n0 = i0 & 63;
      unsigned short v[8];
      if (isb) {
        const u16x8 u = *(const u16x8*)(Wus + i0);
#pragma unroll
        for (int j = 0; j < 8; ++j) v[j] = u[j];
      } else {
        const float4 f0 = *(const float4*)(Wf + i0);
        const float4 f1 = *(const float4*)(Wf + i0 + 4);
        v[0] = f2b(f0.x); v[1] = f2b(f0.y); v[2] = f2b(f0.z); v[3] = f2b(f0.w);
        v[4] = f2b(f1.x); v[5] = f2b(f1.y); v[6] = f2b(f1.z); v[7] = f2b(f1.w);
      }
#pragma unroll
      for (int j = 0; j < 8; ++j) Wl[(n0 + j) * ST + k] = v[j];
    }
  }
  __syncthreads();

  unsigned short* myC = &Cl[w][0];
#pragma unroll
  for (int gi = 0; gi < 2; ++gi) {
    const int g = (gi == 0) ? wid : g1;
    f32x4 acc[4] = {{0.f, 0.f, 0.f, 0.f}, {0.f, 0.f, 0.f, 0.f},
                    {0.f, 0.f, 0.f, 0.f}, {0.f, 0.f, 0.f, 0.f}};
#pragma unroll
    for (int kt = 0; kt < KT; ++kt) {
      const int koff = kt * 32 + quad * 8;
#pragma unroll
      for (int nt = 0; nt < 4; ++nt) {
        const bf16x8 Bf = *(const bf16x8*)&Wl[(nt * 16 + l16) * ST + koff];
        acc[nt] = __builtin_amdgcn_mfma_f32_16x16x32_bf16(A[gi][kt], Bf, acc[nt], 0, 0, 0);
      }
    }
    const int rowD = quad * 4;
#pragma unroll
    for (int r = 0; r < 4; ++r) {
      const int nodeW = min((g << 4) + rowD + r, N - 1);
      const float f = SCALE ? norm_src[nodeW] : 1.0f;
#pragma unroll
      for (int nt = 0; nt < 4; ++nt)
        myC[(rowD + r) * CST + nt * 16 + l16] = f2b(SCALE ? acc[nt][r] * f : acc[nt][r]);
    }
    __builtin_amdgcn_sched_barrier(0);
    const int row2 = lane >> 2;
    const int c0 = (lane & 3) * 16;
    const int node = (g << 4) + row2;
    if (node < N) {
      const u16x8 v0 = *(const u16x8*)&myC[row2 * CST + c0];
      const u16x8 v1 = *(const u16x8*)&myC[row2 * CST + c0 + 8];
      *(u16x8*)(out + (size_t)node * 64 + c0) = v0;
      *(u16x8*)(out + (size_t)node * 64 + c0 + 8) = v1;
    }
  }
}

// ---------------- MFMA aggregation (SpMM, segment-indicator A) + fused next-gemm -----
__device__ __forceinline__ void agg_chunk_compute(unsigned trbase, int cb32, int lo,
                                                  unsigned span, int quad, f32x4* acc) {
  const int posbase = cb32 + (quad << 2);
  const unsigned u0 = (unsigned)(posbase - lo);
  bf16x8 Af;
#pragma unroll
  for (int j = 0; j < 8; ++j) {
    const unsigned off = (j < 4) ? (unsigned)j : (unsigned)(12 + j);
    Af[j] = ((u0 + off) < span) ? (short)0x3F80 : (short)0;
  }
  s16x4 t0[4], t1[4];
#pragma unroll
  for (int nt = 0; nt < 4; ++nt) {
    const unsigned a = trbase + (unsigned)(nt * 1024);
    asm volatile("ds_read_b64_tr_b16 %0, %1" : "=v"(t0[nt]) : "v"(a) : "memory");
    asm volatile("ds_read_b64_tr_b16 %0, %1 offset:512" : "=v"(t1[nt]) : "v"(a) : "memory");
  }
  asm volatile("s_waitcnt lgkmcnt(0)" ::: "memory");
  __builtin_amdgcn_sched_barrier(0);
#pragma unroll
  for (int nt = 0; nt < 4; ++nt) {
    bf16x8 Bf;
    Bf[0] = t0[nt][0]; Bf[1] = t0[nt][1]; Bf[2] = t0[nt][2]; Bf[3] = t0[nt][3];
    Bf[4] = t1[nt][0]; Bf[5] = t1[nt][1]; Bf[6] = t1[nt][2]; Bf[7] = t1[nt][3];
    acc[nt] = __builtin_amdgcn_mfma_f32_16x16x32_bf16(Af, Bf, acc[nt], 0, 0, 0);
  }
}

template <bool LAST, bool FUSE>
__global__ void __launch_bounds__(256) k_aggregate(
    const unsigned short* __restrict__ proj,
    const int* __restrict__ edgeSrc, const int* __restrict__ rowStart,
    const float* __restrict__ norm_dst, const float* __restrict__ norm_src,
    const void* __restrict__ bias, const int* __restrict__ flag,
    const unsigned short* __restrict__ WT, int N, int E, void* __restrict__ outp) {
  __shared__ unsigned short lds[4][2048];  // 4 KB per wave: [32 edges][64 cols]
  const bool isb = (*flag != 0);
  const int tid = threadIdx.x;
  const int w = tid >> 6;
  const int lane = tid & 63;
  const int l16 = lane & 15;
  const int quad = lane >> 4;
  const int e32 = lane & 31;
  const int p = lane >> 5;

  const int wid = blockIdx.x * 4 + w;
  const int g0 = wid * 8;

  float bcol[4];
#pragma unroll
  for (int nt = 0; nt < 4; ++nt) {
    const int col = nt * 16 + l16;
    bcol[nt] = isb ? b2f(((const unsigned short*)bias)[col]) : ((const float*)bias)[col];
  }

  const int cb = rowStart[min(g0, N)];
  const int ce = rowStart[min(g0 + 8, N)];
  const int L = ce - cb;
  const int nch = (L + 31) >> 5;

  const int rsi = min(g0 + min(l16, 8), N);
  const int rsj = min(g0 + min(l16 + 1, 8), N);
  const int lo = rowStart[rsi];
  const unsigned span = (unsigned)(rowStart[rsj] - lo);

  int idxc[6];
#pragma unroll
  for (int t = 0; t < 6; ++t) {
    const int pos = min(cb + t * 32 + e32, E - 1);
    idxc[t] = edgeSrc[pos];
  }

  unsigned short* myl = &lds[w][0];
  unsigned wofs[4];
#pragma unroll
  for (int q = 0; q < 4; ++q) {
    const int n0 = p * 32 + q * 8;
    wofs[q] = (unsigned)((n0 >> 4) * 512 + e32 * 16 + (n0 & 15));
  }
  const unsigned trbase = (unsigned)(uintptr_t)myl + (unsigned)lane * 8u;

  f32x4 acc[4] = {{0.f, 0.f, 0.f, 0.f}, {0.f, 0.f, 0.f, 0.f},
                  {0.f, 0.f, 0.f, 0.f}, {0.f, 0.f, 0.f, 0.f}};

  i32x4 gb[2][4];
#define AGG_ISSUE(t, b)                                                         \
  {                                                                             \
    const unsigned short* rp = proj + (size_t)idxc[t] * 64 + p * 32;            \
    gb[b][0] = *(const i32x4*)(rp);                                             \
    gb[b][1] = *(const i32x4*)(rp + 8);                                         \
    gb[b][2] = *(const i32x4*)(rp + 16);                                        \
    gb[b][3] = *(const i32x4*)(rp + 24);                                        \
  }
  if (0 < nch) AGG_ISSUE(0, 0);
  if (1 < nch) AGG_ISSUE(1, 1);

#pragma unroll
  for (int tt = 0; tt < 6; ++tt) {
    if (tt < nch) {
#pragma unroll
      for (int q = 0; q < 4; ++q) *(i32x4*)(myl + wofs[q]) = gb[tt & 1][q];
      if (tt + 2 < 6 && tt + 2 < nch) AGG_ISSUE(tt + 2, tt & 1);
      asm volatile("s_waitcnt lgkmcnt(0)" ::: "memory");
      agg_chunk_compute(trbase, cb + tt * 32, lo, span, quad, acc);
    }
  }
  for (int t = 6; t < nch; ++t) {
    const int pos = min(cb + t * 32 + e32, E - 1);
    const int idx = edgeSrc[pos];
    const unsigned short* rp = proj + (size_t)idx * 64 + p * 32;
    i32x4 g4[4];
    g4[0] = *(const i32x4*)(rp);
    g4[1] = *(const i32x4*)(rp + 8);
    g4[2] = *(const i32x4*)(rp + 16);
    g4[3] = *(const i32x4*)(rp + 24);
#pragma unroll
    for (int q = 0; q < 4; ++q) *(i32x4*)(myl + wofs[q]) = g4[q];
    asm volatile("s_waitcnt lgkmcnt(0)" ::: "memory");
    agg_chunk_compute(trbase, cb + t * 32, lo, span, quad, acc);
  }
#undef AGG_ISSUE

  if constexpr (FUSE) {
    // ---- fused epilogue: h -> hT (aliased) -> h @ WT -> proj stores ----
    __syncthreads();  // all waves done with their gather tiles before aliasing
    unsigned short* hT = &lds[0][0];  // 32 x 72 (144B row stride, 16B-aligned)
    const int r0 = (w & 1) * 16;
    const int cb2 = (w >> 1) * 32;
    // B-fragments from the 8KB pre-transposed WT table (L2-hot, 4x16B/lane)
    bf16x8 Bfr[2][2];
#pragma unroll
    for (int kt = 0; kt < 2; ++kt) {
      const int koff = kt * 32 + quad * 8;
#pragma unroll
      for (int nt = 0; nt < 2; ++nt)
        Bfr[kt][nt] = *(const bf16x8*)(WT + (size_t)(cb2 + nt * 16 + l16) * 64 + koff);
    }
#pragma unroll
    for (int reg = 0; reg < 4; ++reg) {
      const int row = quad * 4 + reg;
      if (row < 8) {
        const int node = min(g0 + row, N - 1);
        const float nd = norm_dst[node];
        const float esc = norm_src[node];
#pragma unroll
        for (int nt = 0; nt < 4; ++nt) {
          const float x = fmaxf(fmaf(acc[nt][reg], nd, bcol[nt]), 0.f) * esc;
          hT[(w * 8 + row) * 72 + nt * 16 + l16] = f2b(x);
        }
      }
    }
    __syncthreads();
    // each wave: 16 rows x 32 cols of proj = h @ W
    bf16x8 Afr[2];
#pragma unroll
    for (int kt = 0; kt < 2; ++kt)
      Afr[kt] = *(const bf16x8*)&hT[(r0 + l16) * 72 + kt * 32 + quad * 8];
    f32x4 acc2[2] = {{0.f, 0.f, 0.f, 0.f}, {0.f, 0.f, 0.f, 0.f}};
#pragma unroll
    for (int kt = 0; kt < 2; ++kt)
#pragma unroll
      for (int nt = 0; nt < 2; ++nt)
        acc2[nt] = __builtin_amdgcn_mfma_f32_16x16x32_bf16(Afr[kt], Bfr[kt][nt], acc2[nt], 0, 0, 0);
    __syncthreads();  // all A LDS reads complete before hT is overwritten
#pragma unroll
    for (int nt = 0; nt < 2; ++nt)
#pragma unroll
      for (int reg = 0; reg < 4; ++reg) {
        const int row = r0 + quad * 4 + reg;
        hT[row * 72 + cb2 + nt * 16 + l16] = f2b(acc2[nt][reg]);
      }
    __syncthreads();
    const int row = tid >> 3;
    const int c0 = (tid & 7) * 8;
    const int node = blockIdx.x * 32 + row;
    if (node < N) {
      *(u16x8*)((unsigned short*)outp + (size_t)node * 64 + c0) =
          *(const u16x8*)&hT[row * 72 + c0];
    }
  } else {
    // ---- LAST epilogue: finalize -> stage[w] -> coalesced stores ----
    if (!isb) {
      float* fs = (float*)myl;
#pragma unroll
      for (int reg = 0; reg < 4; ++reg) {
        const int row = quad * 4 + reg;
        if (row < 8) {
          const int node = min(g0 + row, N - 1);
          const float nd = norm_dst[node];
#pragma unroll
          for (int nt = 0; nt < 4; ++nt)
            fs[row * 64 + nt * 16 + l16] = fmaxf(fmaf(acc[nt][reg], nd, bcol[nt]), 0.f);
        }
      }
      asm volatile("s_waitcnt lgkmcnt(0)" ::: "memory");
      __builtin_amdgcn_sched_barrier(0);
      const int r = lane >> 3;
      const int c0 = (lane & 7) * 8;
      const int node = g0 + r;
      if (node < N) {
        const float4 v0 = *(const float4*)&fs[r * 64 + c0];
        const float4 v1 = *(const float4*)&fs[r * 64 + c0 + 4];
        float* of = (float*)outp + (size_t)node * 64 + c0;
        *(float4*)of = v0;
        *(float4*)(of + 4) = v1;
      }
    } else {
#pragma unroll
      for (int reg = 0; reg < 4; ++reg) {
        const int row = quad * 4 + reg;
        if (row < 8) {
          const int node = min(g0 + row, N - 1);
          const float nd = norm_dst[node];
#pragma unroll
          for (int nt = 0; nt < 4; ++nt) {
            const float x = fmaxf(fmaf(acc[nt][reg], nd, bcol[nt]), 0.f);
            myl[row * 64 + nt * 16 + l16] = f2b(x);
          }
        }
      }
      asm volatile("s_waitcnt lgkmcnt(0)" ::: "memory");
      __builtin_amdgcn_sched_barrier(0);
      if (lane < 32) {
        const int r = lane >> 2;
        const int c0 = (lane & 3) * 16;
        const int node = g0 + r;
        if (node < N) {
          const u16x8 v0 = *(const u16x8*)&myl[r * 64 + c0];
          const u16x8 v1 = *(const u16x8*)&myl[r * 64 + c0 + 8];
          *(u16x8*)((unsigned short*)outp + (size_t)node * 64 + c0) = v0;
          *(u16x8*)((unsigned short*)outp + (size_t)node * 64 + c0 + 8) = v1;
        }
      }
    }
  }
}

extern "C" void kernel_launch(void* const* d_in, const int* in_sizes, int n_in,
                              void* d_out, int out_size, void* d_ws, size_t ws_size,
                              hipStream_t stream) {
  const void* features = d_in[0];
  const void* W0 = d_in[1];
  const void* b0 = d_in[2];
  const void* W1 = d_in[3];
  const void* b1 = d_in[4];
  const void* W2 = d_in[5];
  const void* b2 = d_in[6];
  const int* src = (const int*)d_in[7];
  const int* dst = (const int*)d_in[8];
  const int N = in_sizes[0] / 128;
  const int E = in_sizes[7];
  const int NBUCK = (N + 255) >> 8;
  const int M = NBUCK * 256;
  const int M2 = 2 * M;

  char* w = (char*)d_ws;
  size_t off = 0;
  auto alloc = [&](size_t bytes) {
    void* p = w + off;
    off = (off + bytes + 255) & ~(size_t)255;
    return p;
  };
  int* flag = (int*)alloc(4);
  int* rowStart = (int*)alloc((size_t)(N + 1) * 4);
  int* counts = (int*)alloc((size_t)M2 * 4);
  int* bsums = (int*)alloc(1024 * 4);
  float* norm_src = (float*)alloc((size_t)N * 4);
  float* norm_dst = (float*)alloc((size_t)N * 4);
  int* tmp = (int*)alloc((size_t)E * 4);
  unsigned char* tmp2 = (unsigned char*)alloc((size_t)E);
  int* edgeSrc = (int*)alloc((size_t)E * 4);
  unsigned short* projA = (unsigned short*)alloc((size_t)N * 64 * 2);  // bf16
  unsigned short* projB = (unsigned short*)alloc((size_t)N * 64 * 2);  // bf16
  unsigned short* WT1 = (unsigned short*)alloc(64 * 64 * 2);
  unsigned short* WT2 = (unsigned short*)alloc(64 * 64 * 2);

  const size_t lds_nb = (size_t)NBUCK * 2 * 4;  // dual hist/cursors
  const int G16 = (N + 15) / 16;                // 16-row groups
  const int GB = (G16 + 7) / 8;                 // exactly 2 groups per wave

  // CSR build — zero global atomics end-to-end, no memset needed.
  k_passA<<<257, 1024, lds_nb, stream>>>(src, dst, E, NBUCK, M, counts,
                                         (const unsigned short*)features, flag);
  const int NB2 = (M2 + 255) / 256;  // == 2*NBUCK
  k_scan1<<<NB2, 256, 0, stream>>>(counts, M2, bsums);
  k_scan2<<<9, 1024, 0, stream>>>(bsums, NB2, rowStart, N, E, W1, W2, flag, WT1, WT2);
  k_scan3<<<NB2, 256, 0, stream>>>(counts, M2, bsums);
  k_passC<<<256, 1024, lds_nb, stream>>>(src, dst, E, NBUCK, M, counts, tmp, tmp2);
  k_passD<<<NBUCK, 1024, 0, stream>>>(tmp, tmp2, counts, NBUCK, M, N, E,
                                      rowStart, edgeSrc, norm_src, norm_dst);

  const int AB = (((N + 7) / 8) + 3) / 4;  // 8 nodes/wave, 4 waves/block (32/block)
  // layer 0 gemm (ns folded into epilogue)
  k_gemm<128, true, true><<<GB, 256, 0, stream>>>(features, W0, flag, norm_src, N, projA);
  // agg0 + fused gemm1 -> projB
  k_aggregate<false, true><<<AB, 256, 0, stream>>>(projA, edgeSrc, rowStart, norm_dst,
                                                   norm_src, b0, flag, WT1, N, E, projB);
  // agg1 + fused gemm2 -> projA
  k_aggregate<false, true><<<AB, 256, 0, stream>>>(projB, edgeSrc, rowStart, norm_dst,
                                                   norm_src, b1, flag, WT2, N, E, projA);
  // agg2 (LAST) -> d_out
  k_aggregate<true, false><<<AB, 256, 0, stream>>>(projA, edgeSrc, rowStart, norm_dst,
                                                   norm_src, b2, flag, nullptr, N, E, d_out);
}